// Round 19
// baseline (113.109 us; speedup 1.0000x reference)
//
#include <hip/hip_runtime.h>

// QuantizeEMAReset forward (eval): VQ quantize + commit loss + perplexity/usage.
// z: [16,4096,64] fp32 -> N=65536 tokens, C=64. codebook: [1024,64] fp32.
// out: [z_q_bar (4194304 f32), commit_loss, ppl, usage] flat.
//
// R19: 2-way K-split for TLP. Plateau evidence: 6 structures (R7..R18) all
// 70-78us quant at 4 blocks/CU (grid-capped), every pipe <40% -> latency-
// bound on dependent chains with only 16 waves/CU. Split: 2048 blocks
// (grp=blk&1023 -> 64 tokens; split=blk>>10 -> half codebook, 32 tiles),
// lean 20KB LDS (4-slot x 1-tile ring + cn_lds; NO epilogue) -> 7 blocks/CU
// = 28 waves/CU. Cross-split merge is EXACT: each block resolves its local
// winner (R13 top-2 + MARGIN rescue, proven absmax 0.0), computes the
// winner's exact fp32 distance (bit-exact R1 chain) and publishes
// atomicMin(bestq[tok], exact_key|idx) -- R2/R3-proven machinery; global
// argmin + jnp first-min tie rule hold regardless of fp16 error.
// Epilogue -> gather kernel (R2's proven 1-thread/token form).
//
// ws float-index map:
//   [0,1024)        cnorm
//   [1024,2048)     counts
//   [2048,2304)     loss partials (256 gather blocks)
//   [20480,86016)   cbhl tile stream: 64 tiles x 2048 halves (hi 1KB | lo 1KB)
//   [90112,221184)  bestq[65536] u64 (exact-keyed global argmin)  ~864KB total

typedef _Float16 half8 __attribute__((ext_vector_type(8)));
typedef float f32x4 __attribute__((ext_vector_type(4)));

#define NTOK 65536
#define KCODE 1024
#define OUT_SCALARS 4194304
#define MARGIN 1e-3f

#define WS_CNT   1024
#define WS_LOSS  2048
#define WS_CBHL  20480
#define WS_BESTQ 90112

static __device__ __forceinline__ unsigned int order_key(float f) {
    unsigned int u = __float_as_uint(f);
    unsigned int mask = (u >> 31) ? 0xFFFFFFFFu : 0x80000000u;
    return u ^ mask;   // monotone: a<b (float) <=> key(a)<key(b) (uint)
}
static __device__ __forceinline__ float key_to_float(unsigned int k) {
    unsigned int u = (k & 0x80000000u) ? (k ^ 0x80000000u) : ~k;
    return __uint_as_float(u);   // inverse of order_key
}
static __device__ __forceinline__ unsigned long long umin64(unsigned long long a,
                                                            unsigned long long b) {
    return a < b ? a : b;
}
static __device__ __forceinline__ unsigned long long umax64(unsigned long long a,
                                                            unsigned long long b) {
    return a > b ? a : b;
}

__global__ void prep_kernel(const float* __restrict__ cb, float* __restrict__ ws) {
    const int i = blockIdx.x * 256 + threadIdx.x;   // 0..65535
    ((unsigned long long*)(ws + WS_BESTQ))[i] = ~0ull;
    if (i >= 1024) return;
    const int k = i;
    const float4* cb4 = (const float4*)cb;
    float s = 0.f;
#pragma unroll
    for (int j = 0; j < 16; ++j) {
        float4 v = cb4[k * 16 + j];
        s = fmaf(v.x, v.x, s);
        s = fmaf(v.y, v.y, s);
        s = fmaf(v.z, v.z, s);
        s = fmaf(v.w, v.w, s);
    }
    ws[k] = s;             // cnorm: exact R1 chain
    ws[WS_CNT + k] = 0.f;  // zero histogram

    // swizzled tile stream: tile = k>>4, c = k&15
    _Float16* base = (_Float16*)(ws + WS_CBHL) + (size_t)(k >> 4) * 2048 + (k & 15) * 64;
    const int c = k & 15;
#pragma unroll
    for (int d8 = 0; d8 < 8; ++d8) {
        float4 a = cb4[k * 16 + 2 * d8], b = cb4[k * 16 + 2 * d8 + 1];
        float xf[8] = {a.x, a.y, a.z, a.w, b.x, b.y, b.z, b.w};
        half8 h, lo;
#pragma unroll
        for (int i2 = 0; i2 < 8; ++i2) {
            _Float16 hi = (_Float16)xf[i2];
            h[i2] = hi;
            lo[i2] = (_Float16)((xf[i2] - (float)hi) * 4096.f);  // scaled: no f16 denorm flush
        }
        const int pos = ((d8 + c) & 7) * 8;   // 16B-slot rotation (bank spread)
        *(half8*)(base + pos) = h;
        *(half8*)(base + 1024 + pos) = lo;
    }
}

__launch_bounds__(256, 7)
__global__ void quant_kernel(const float* __restrict__ z,
                             const float* __restrict__ cb,
                             float* __restrict__ ws) {
    const int t = threadIdx.x, blk = blockIdx.x;
    const int grp = blk & 1023, split = blk >> 10;
    const int w = t >> 6, l = t & 63;
    const int cl = l & 15, g = l >> 4;
    const int tok0 = grp * 64;
    const int tokL = w * 16 + cl;
    const int tokG = tok0 + tokL;
    const int TB = split * 32;               // this block's first global tile

    __shared__ __align__(16) _Float16 ring[4][2048];   // 4-slot x 1-tile ring, 16KB
    __shared__ __align__(16) float cn_lds[1024];

    // ---- stage cnorm to LDS ----
    *(float4*)&cn_lds[t * 4] = *(const float4*)(ws + t * 4);

    // ---- B fragments: ONE token set of 16 (persistent regs; proven) ----
    half8 zh[2], zl[2];
    {
        const float4* z4 = (const float4*)z + (size_t)tokG * 16;
#pragma unroll
        for (int q = 0; q < 2; ++q) {
            float4 a = z4[2 * g + 8 * q], b = z4[2 * g + 8 * q + 1];
            float xf[8] = {a.x, a.y, a.z, a.w, b.x, b.y, b.z, b.w};
#pragma unroll
            for (int i = 0; i < 8; ++i) {
                _Float16 h = (_Float16)xf[i];
                zh[q][i] = h;
                zl[q][i] = (_Float16)((xf[i] - (float)h) * 4096.f);
            }
        }
    }

    // PIN: z-loads + own LDS writes done; in-loop vmcnt counts ONLY DMA stream.
    asm volatile("s_waitcnt vmcnt(0) lgkmcnt(0)" ::: "memory");
    __builtin_amdgcn_sched_barrier(0);

    // per-wave DMA src: wave w stages quarter w of each tile (1KB/tile)
    const char* dma_src = (const char*)(ws + WS_CBHL) + (size_t)TB * 4096 + w * 1024 + l * 16;
    const int rot = (g + cl) & 7;
    const int o0 = cl * 64 + rot * 8;
    const int o1 = cl * 64 + (rot ^ 4) * 8;

    // prologue: tiles 0,1,2 in flight (3 DMAs/wave)
#pragma unroll
    for (int p = 0; p < 3; ++p)
        __builtin_amdgcn_global_load_lds(
            (const __attribute__((address_space(1))) void*)(dma_src + p * 4096),
            (__attribute__((address_space(3))) void*)&ring[p][w * 512], 16, 0, 0);

    unsigned long long K1r = ~0ull, K2r = ~0ull;   // running keyed top-2

#define TILE_COMPUTE(ti, SLOT)                                                        \
    {                                                                                 \
        const _Float16* tp = &ring[SLOT][0];                                          \
        half8 H0 = *(const half8*)(tp + o0);                                          \
        half8 H1 = *(const half8*)(tp + o1);                                          \
        half8 L0 = *(const half8*)(tp + 1024 + o0);                                   \
        half8 L1 = *(const half8*)(tp + 1024 + o1);                                   \
        float4 cnv = *(const float4*)&cn_lds[(TB + (ti)) * 16 + 4 * g];               \
        const float cna[4] = {cnv.x, cnv.y, cnv.z, cnv.w};                            \
        f32x4 a1 = {0.f,0.f,0.f,0.f}, a2 = {0.f,0.f,0.f,0.f};                         \
        a1 = __builtin_amdgcn_mfma_f32_16x16x32_f16(H0, zh[0], a1, 0, 0, 0);          \
        a1 = __builtin_amdgcn_mfma_f32_16x16x32_f16(H1, zh[1], a1, 0, 0, 0);          \
        a2 = __builtin_amdgcn_mfma_f32_16x16x32_f16(H0, zl[0], a2, 0, 0, 0);          \
        a2 = __builtin_amdgcn_mfma_f32_16x16x32_f16(H1, zl[1], a2, 0, 0, 0);          \
        a2 = __builtin_amdgcn_mfma_f32_16x16x32_f16(L0, zh[0], a2, 0, 0, 0);          \
        a2 = __builtin_amdgcn_mfma_f32_16x16x32_f16(L1, zh[1], a2, 0, 0, 0);          \
        unsigned long long kk[4];                                                     \
        _Pragma("unroll")                                                             \
        for (int r = 0; r < 4; ++r) {                                                 \
            float dot = fmaf(a2[r], 2.44140625e-4f, a1[r]);                           \
            float d = fmaf(-2.f, dot, cna[r]);            /* exact same chain */      \
            kk[r] = ((unsigned long long)order_key(d) << 32)                          \
                    | (unsigned)((TB + (ti)) * 16 + 4 * g + r);                       \
        }                                                                             \
        unsigned long long lo01 = umin64(kk[0], kk[1]);                               \
        unsigned long long hi01 = umax64(kk[0], kk[1]);                               \
        unsigned long long lo23 = umin64(kk[2], kk[3]);                               \
        unsigned long long hi23 = umax64(kk[2], kk[3]);                               \
        unsigned long long m1 = umin64(lo01, lo23);                                   \
        unsigned long long m2 = umin64(umax64(lo01, lo23), umin64(hi01, hi23));       \
        unsigned long long nlo = umin64(K1r, m1);                                     \
        unsigned long long nhi = umax64(K1r, m1);                                     \
        K2r = umin64(nhi, umin64(K2r, m2));                                           \
        K1r = nlo;                                                                    \
    }

    // phase T: vmcnt (tile T landed; T+1,T+2 in flight), barrier, issue T+3, compute T.
#define PHASE(T, SLOT, SLOT2, VM, ISSUE)                                              \
    {                                                                                 \
        asm volatile("s_waitcnt vmcnt(" VM ")" ::: "memory");                         \
        asm volatile("s_barrier" ::: "memory");                                       \
        if (ISSUE)                                                                    \
            __builtin_amdgcn_global_load_lds(                                         \
                (const __attribute__((address_space(1))) void*)(dma_src + ((T) + 3) * 4096), \
                (__attribute__((address_space(3))) void*)&ring[SLOT2][w * 512],       \
                16, 0, 0);                                                            \
        TILE_COMPUTE(T, SLOT)                                                         \
    }

    // phases 0..27 (7 x 4, static slots), issuing tiles 3..30
    for (int i4 = 0; i4 < 28; i4 += 4) {
        PHASE(i4 + 0, 0, 3, "2", 1)
        PHASE(i4 + 1, 1, 0, "2", 1)
        PHASE(i4 + 2, 2, 1, "2", 1)
        PHASE(i4 + 3, 3, 2, "2", 1)
    }
    PHASE(28, 0, 3, "2", 1)   // issues tile 31
    PHASE(29, 1, 0, "2", 0)
    PHASE(30, 2, 0, "1", 0)
    PHASE(31, 3, 0, "0", 0)
#undef PHASE
#undef TILE_COMPUTE

    // ---- keyed top-2 merge across the 4 lanes of each token (xor 16, 32) ----
    unsigned long long k1 = K1r, k2 = K2r;
#pragma unroll
    for (int off = 16; off <= 32; off <<= 1) {
        unsigned long long ok1 = __shfl_xor(k1, off, 64);
        unsigned long long ok2 = __shfl_xor(k2, off, 64);
        unsigned long long lo = umin64(k1, ok1);
        unsigned long long hi = umax64(k1, ok1);
        k2 = umin64(hi, umin64(k2, ok2));
        k1 = lo;
    }

    if (l < 16) {
        int fidx = (int)(unsigned)(k1 & 0xFFFFFFFFull);
        const float d1f = key_to_float((unsigned)(k1 >> 32));
        const float d2f = key_to_float((unsigned)(k2 >> 32));
        const float4* zr = (const float4*)z + (size_t)tokG * 16;
        if (d2f - d1f < MARGIN) {
            // exact fp32 rescore of the two local candidates (bit-exact R1 chain)
            const int ia = fidx;
            const int ib = (int)(unsigned)(k2 & 0xFFFFFFFFull);
            const float4* ca = (const float4*)cb + (size_t)ia * 16;
            const float4* cbp = (const float4*)cb + (size_t)ib * 16;
            float sa = 0.f, sb = 0.f;
#pragma unroll
            for (int j = 0; j < 16; ++j) {
                float4 xv = zr[j];
                float4 va = ca[j], vb = cbp[j];
                sa = fmaf(xv.x, va.x, sa); sb = fmaf(xv.x, vb.x, sb);
                sa = fmaf(xv.y, va.y, sa); sb = fmaf(xv.y, vb.y, sb);
                sa = fmaf(xv.z, va.z, sa); sb = fmaf(xv.z, vb.z, sb);
                sa = fmaf(xv.w, va.w, sa); sb = fmaf(xv.w, vb.w, sb);
            }
            const float ea = fmaf(-2.f, sa, cn_lds[ia]);
            const float eb = fmaf(-2.f, sb, cn_lds[ib]);
            const unsigned long long ka = ((unsigned long long)order_key(ea) << 32) | (unsigned)ia;
            const unsigned long long kb = ((unsigned long long)order_key(eb) << 32) | (unsigned)ib;
            fidx = (int)(unsigned)(umin64(ka, kb) & 0xFFFFFFFFull);
        }
        // exact distance of the local winner -> global exact-key merge
        {
            const float4* cw = (const float4*)cb + (size_t)fidx * 16;
            float s = 0.f;
#pragma unroll
            for (int j = 0; j < 16; ++j) {
                float4 xv = zr[j];
                float4 cv = cw[j];
                s = fmaf(xv.x, cv.x, s);
                s = fmaf(xv.y, cv.y, s);
                s = fmaf(xv.z, cv.z, s);
                s = fmaf(xv.w, cv.w, s);
            }
            const float e = fmaf(-2.f, s, cn_lds[fidx]);   // exact R1 distance
            unsigned long long ek = ((unsigned long long)order_key(e) << 32) | (unsigned)fidx;
            atomicMin((unsigned long long*)(ws + WS_BESTQ) + tokG, ek);
        }
    }
}

// Gather (R2-proven form): 1 thread/token; reads global winner, writes z_q_bar,
// histogram, block loss partial.
__global__ void gather_kernel(const float* __restrict__ z,
                              const float* __restrict__ cb,
                              float* __restrict__ out,
                              float* __restrict__ ws) {
    const int tok = blockIdx.x * 256 + threadIdx.x;
    const unsigned long long* bq = (const unsigned long long*)(ws + WS_BESTQ);
    const int idx = (int)(unsigned)bq[tok];

    atomicAdd(&ws[WS_CNT + idx], 1.0f);   // integer-valued adds: exact, order-indep

    const float4* z4 = (const float4*)z + (size_t)tok * 16;
    const float4* cq = (const float4*)cb + (size_t)idx * 16;
    float4* o4 = (float4*)out + (size_t)tok * 16;
    float ssum = 0.f;
#pragma unroll
    for (int j = 0; j < 16; ++j) {
        float4 xv = z4[j];
        float4 qv = cq[j];
        float4 ov;
        float dx;
        dx = qv.x - xv.x; ov.x = xv.x + dx; ssum = fmaf(dx, dx, ssum);
        dx = qv.y - xv.y; ov.y = xv.y + dx; ssum = fmaf(dx, dx, ssum);
        dx = qv.z - xv.z; ov.z = xv.z + dx; ssum = fmaf(dx, dx, ssum);
        dx = qv.w - xv.w; ov.w = xv.w + dx; ssum = fmaf(dx, dx, ssum);
        o4[j] = ov;
    }

    float v = ssum * (1.f / 64.f);
#pragma unroll
    for (int off = 32; off > 0; off >>= 1) v += __shfl_down(v, off, 64);
    __shared__ float wsum[4];
    int lane = threadIdx.x & 63, wid = threadIdx.x >> 6;
    if (lane == 0) wsum[wid] = v;
    __syncthreads();
    if (threadIdx.x == 0)
        ws[WS_LOSS + blockIdx.x] = wsum[0] + wsum[1] + wsum[2] + wsum[3];
}

// Reduce-only final (shuffle trees; R12/R13-proven logic). 1 block x 1024 thr.
__global__ void final_kernel(const float* __restrict__ ws, float* __restrict__ out) {
    const int t = threadIdx.x;          // 0..1023
    const int l = t & 63, wv = t >> 6;  // 16 waves
    __shared__ float rbuf[16];

#define BLOCK_REDUCE(VAR, EXPR)                                             \
    float VAR;                                                              \
    {                                                                       \
        float v_ = (EXPR);                                                  \
        _Pragma("unroll")                                                   \
        for (int off = 32; off > 0; off >>= 1) v_ += __shfl_down(v_, off, 64); \
        if (l == 0) rbuf[wv] = v_;                                          \
        __syncthreads();                                                    \
        float r_ = (t < 16) ? rbuf[t] : 0.f;                                \
        if (wv == 0) {                                                      \
            _Pragma("unroll")                                               \
            for (int off = 8; off > 0; off >>= 1) r_ += __shfl_down(r_, off, 64); \
            if (l == 0) rbuf[0] = r_;                                       \
        }                                                                   \
        __syncthreads();                                                    \
        VAR = rbuf[0];                                                      \
        __syncthreads();                                                    \
    }

    const float c = ws[WS_CNT + t];
    BLOCK_REDUCE(totraw, c)
    const float total = fmaxf(totraw, 1e-6f);
    const float p = c / total;
    BLOCK_REDUCE(ent, p * logf(p + 1e-7f))
    BLOCK_REDUCE(used, (c >= 1.f) ? 1.f : 0.f)
    BLOCK_REDUCE(loss, (t < 256) ? ws[WS_LOSS + t] : 0.f)
#undef BLOCK_REDUCE

    if (t == 0) {
        out[OUT_SCALARS + 0] = loss * (1.f / (float)NTOK);
        out[OUT_SCALARS + 1] = expf(-ent);
        out[OUT_SCALARS + 2] = used * (1.f / (float)KCODE);
    }
}

extern "C" void kernel_launch(void* const* d_in, const int* in_sizes, int n_in,
                              void* d_out, int out_size, void* d_ws, size_t ws_size,
                              hipStream_t stream) {
    const float* z  = (const float*)d_in[0];
    const float* cb = (const float*)d_in[1];
    float* out = (float*)d_out;
    float* ws  = (float*)d_ws;   // ~864 KB used

    prep_kernel  <<<256, 256, 0, stream>>>(cb, ws);
    quant_kernel <<<2048, 256, 0, stream>>>(z, cb, ws);
    gather_kernel<<<256, 256, 0, stream>>>(z, cb, out, ws);
    final_kernel <<<1, 1024, 0, stream>>>(ws, out);
}